// Round 1
// 236.976 us; speedup vs baseline: 1.0591x; 1.0591x over previous
//
#include <hip/hip_runtime.h>

// Problem constants (from reference)
#define B_  4
#define N_  1
#define D_  48
#define H_  32
#define W_  88
#define C_  64
#define NX_ 200
#define NY_ 200
#define NZ_ 1
#define NPRIME (B_ * N_ * D_ * H_ * W_)   // 540,672 points
#define NXY    (NX_ * NY_)                // 40,000 bev cells
#define NVOX   (B_ * NXY)                 // 160,000 voxels = 2500 * 64
#define CAP    16                          // bucket capacity (E[n/vox]=1.7)
#define OVFMAX 32768                       // overflow entries (freak-case)

// ---------------------------------------------------------------------------
// Kernel 1 (fused hist+fill): per-point voxel id -> fixed-capacity bucket.
// One thread per point. Replaces hist + scan1 + scan2 + scan3 + fill.
// counts[v] may exceed CAP (gather clamps); extras go to the overflow list
// and are applied exactly by the owning gather block.
// ---------------------------------------------------------------------------
__global__ __launch_bounds__(256)
void bucket_fill(const float* __restrict__ geom,
                 const float* __restrict__ sem,
                 const float* __restrict__ dxp,
                 const float* __restrict__ bxp,
                 int* __restrict__ counts,
                 int* __restrict__ ovfcnt,
                 int* __restrict__ ovfbuf,
                 int* __restrict__ bucket)
{
    int p = blockIdx.x * 256 + threadIdx.x;   // NPRIME = 2112*256 exactly
    int w = p % W_;
    int t = p / W_;
    int h = t % H_;
    int b = (t / H_) / D_;

    float sm = sem[(b * 2 + 1) * (H_ * W_) + h * W_ + w];
    if (!(sm > 0.5f)) return;

    // match reference f32 arithmetic: (geom - (bx - dx/2)) / dx, trunc to 0
    float gxf = (geom[(size_t)p * 3 + 0] - (bxp[0] - dxp[0] * 0.5f)) / dxp[0];
    float gyf = (geom[(size_t)p * 3 + 1] - (bxp[1] - dxp[1] * 0.5f)) / dxp[1];
    float gzf = (geom[(size_t)p * 3 + 2] - (bxp[2] - dxp[2] * 0.5f)) / dxp[2];
    int gx = (int)gxf, gy = (int)gyf, gz = (int)gzf;
    if (gx < 0 || gx >= NX_ || gy < 0 || gy >= NY_ ||
        gz < 0 || gz >= NZ_) return;

    int v = b * NXY + gx * NY_ + gy;          // NZ==1 so gz==0
    int slot = atomicAdd(&counts[v], 1);
    if (slot < CAP) {
        bucket[v * CAP + slot] = p;
    } else {
        int o = atomicAdd(ovfcnt, 1);
        if (o < OVFMAX) { ovfbuf[2 * o] = p; ovfbuf[2 * o + 1] = v; }
    }
}

// ---------------------------------------------------------------------------
// Kernel 2: gather + fused transpose (grouped-float4, hardened).
// Block = 256 thr (4 waves) owns 64 voxels; wave owns 16 voxel-chains.
// Wave split into 4 groups of 16 lanes; group g owns chains {4k+g}.
// Bucket base is v*CAP (no scan needed). Per round: 4 bucket dword loads
// + 4 float4 x-loads, all independent; register accumulation. All indices
// provably in-bounds; dead-slot poison clamped then selected away.
// Then LDS transpose, coalesced store. Overflow (normally 0) applied by
// the owning block AFTER its own stores, with atomics.
// ---------------------------------------------------------------------------
__global__ __launch_bounds__(256)
void bucket_gather(const float* __restrict__ x,
                   const int* __restrict__ counts,
                   const int* __restrict__ bucket,
                   const int* __restrict__ ovfcnt,
                   const int* __restrict__ ovfbuf,
                   float* __restrict__ out)
{
    __shared__ float tile[64][65];      // [vox][ch], +1 pad
    int blk = blockIdx.x;               // 0..2499
    int t    = threadIdx.x;
    int wave = t >> 6;
    int lane = t & 63;
    int g    = lane >> 4;               // group 0..3
    int s    = lane & 15;               // channel quad: ch 4s..4s+3
    int vbase = blk * 64;
    int b   = vbase / NXY;
    int xy0 = vbase % NXY;
    int v0 = vbase + wave * 16;         // this wave's 16 voxels

    // per-voxel counts (wave-uniform, broadcast loads, L2-hot)
    int cnt[16];
    #pragma unroll
    for (int i = 0; i < 16; ++i) cnt[i] = min(counts[v0 + i], CAP);

    int rmax = 0;
    #pragma unroll
    for (int i = 0; i < 16; ++i) rmax = max(rmax, cnt[i]);

    // per-lane select of my 4 chains: chain c = 4k+g (cndmask tree, no
    // dynamic private-array indexing -> no scratch)
    int cg[4], jg[4];
    #pragma unroll
    for (int k = 0; k < 4; ++k) {
        int c0 = cnt[4 * k + 0], c1 = cnt[4 * k + 1];
        int c2 = cnt[4 * k + 2], c3 = cnt[4 * k + 3];
        int cc = (g & 2) ? ((g & 1) ? c3 : c2) : ((g & 1) ? c1 : c0);
        cg[k] = cc;
        jg[k] = (v0 + 4 * k + g) * CAP;     // bucket base for my chain
    }

    float4 acc[4];
    #pragma unroll
    for (int k = 0; k < 4; ++k) acc[k] = make_float4(0.f, 0.f, 0.f, 0.f);

    for (int r = 0; r < rmax; ++r) {
        int e[4];
        #pragma unroll
        for (int k = 0; k < 4; ++k)
            e[k] = bucket[jg[k] + r];       // always in bucket region
        #pragma unroll
        for (int k = 0; k < 4; ++k) {
            e[k] = (r < cg[k]) ? e[k] : 0;  // dead slot -> point 0 (L1-hot)
            e[k] = min(max(e[k], 0), NPRIME - 1);  // defend vs poison content
        }
        float4 val[4];
        #pragma unroll
        for (int k = 0; k < 4; ++k)
            val[k] = *(const float4*)(x + (size_t)e[k] * C_ + s * 4);
        #pragma unroll
        for (int k = 0; k < 4; ++k) {
            if (r < cg[k]) {
                acc[k].x += val[k].x; acc[k].y += val[k].y;
                acc[k].z += val[k].z; acc[k].w += val[k].w;
            }
        }
    }

    // tile[row][4s..4s+3] = acc; per-instr bank usage is exactly 2-way (free)
    #pragma unroll
    for (int k = 0; k < 4; ++k) {
        int row = wave * 16 + 4 * k + g;
        tile[row][4 * s + 0] = acc[k].x;
        tile[row][4 * s + 1] = acc[k].y;
        tile[row][4 * s + 2] = acc[k].z;
        tile[row][4 * s + 3] = acc[k].w;
    }
    __syncthreads();

    // transpose out: lane group writes 256 B contiguous runs of (B,C,XY)
    int col = t & 63;                   // xy within tile
    int rg  = t >> 6;                   // 0..3
    float* dst = out + (size_t)b * C_ * NXY + xy0;
    #pragma unroll
    for (int it = 0; it < 16; ++it) {
        int ch = it * 4 + rg;
        dst[(size_t)ch * NXY + col] = tile[col][ch];
    }

    // overflow (freak case; novf == 0 on this data -> one broadcast load)
    int novf = min(ovfcnt[0], OVFMAX);
    if (novf > 0) {
        __syncthreads();                // our stores above now visible
        __threadfence();
        for (int i = 0; i < novf; ++i) {
            int pv = ovfbuf[2 * i + 1];
            int c0 = pv - vbase;
            if (c0 == t) {              // only t<64 can match; owner applies
                int pp = min(max(ovfbuf[2 * i], 0), NPRIME - 1);
                const float* xr = x + (size_t)pp * C_;
                float* d2 = out + (size_t)b * C_ * NXY + xy0 + c0;
                for (int ch = 0; ch < C_; ++ch)
                    atomicAdd(&d2[(size_t)ch * NXY], xr[ch]);
            }
        }
    }
}

// ---------------------------------------------------------------------------
// Fallback (ws tiny): direct strided atomics into out (B, C, NX, NY).
// ---------------------------------------------------------------------------
__global__ __launch_bounds__(256)
void scatter_direct(const float* __restrict__ x,
                    const float* __restrict__ geom,
                    const float* __restrict__ sem,
                    const float* __restrict__ dxp,
                    const float* __restrict__ bxp,
                    float* __restrict__ out)
{
    int gid = blockIdx.x * 256 + threadIdx.x;
    int p = gid >> 6;
    int c = gid & 63;
    if (p >= NPRIME) return;
    int w = p % W_;
    int t = p / W_;
    int h = t % H_;
    t /= H_;
    int b = t / D_;
    float sm = sem[(b * 2 + 1) * (H_ * W_) + h * W_ + w];
    if (!(sm > 0.5f)) return;
    float gxf = (geom[(size_t)p * 3 + 0] - (bxp[0] - dxp[0] * 0.5f)) / dxp[0];
    float gyf = (geom[(size_t)p * 3 + 1] - (bxp[1] - dxp[1] * 0.5f)) / dxp[1];
    float gzf = (geom[(size_t)p * 3 + 2] - (bxp[2] - dxp[2] * 0.5f)) / dxp[2];
    int gx = (int)gxf, gy = (int)gyf, gz = (int)gzf;
    if (gx < 0 || gx >= NX_ || gy < 0 || gy >= NY_ ||
        gz < 0 || gz >= NZ_) return;
    float val = x[(size_t)p * C_ + c];
    atomicAdd(&out[(((size_t)b * C_ + c) * NX_ + gx) * NY_ + gy], val);
}

// ---------------------------------------------------------------------------
extern "C" void kernel_launch(void* const* d_in, const int* in_sizes, int n_in,
                              void* d_out, int out_size, void* d_ws, size_t ws_size,
                              hipStream_t stream)
{
    const float* x    = (const float*)d_in[0];   // (B,N,D,H,W,C)
    const float* geom = (const float*)d_in[1];   // (B,N,D,H,W,3)
    const float* sem  = (const float*)d_in[2];   // (B*N,2,H,W)
    const float* dxp  = (const float*)d_in[3];   // (3,)
    const float* bxp  = (const float*)d_in[4];   // (3,)
    float* out = (float*)d_out;                  // (B, C, NX, NY)

    // ws layout:
    //   [0]            counts   NVOX ints (640 KB) + ovfcnt right after
    //   [1 MiB]        ovfbuf   OVFMAX*2 ints (256 KB)
    //   [2 MiB]        bucket   NVOX*CAP ints (10.24 MiB)
    char* wsb = (char*)d_ws;
    const size_t MB = 1024 * 1024;
    int* counts = (int*)(wsb + 0 * MB);
    int* ovfcnt = counts + NVOX;
    int* ovfbuf = (int*)(wsb + 1 * MB);
    int* bucket = (int*)(wsb + 2 * MB);
    const size_t wsNeed = 2 * MB + (size_t)NVOX * CAP * sizeof(int);

    if (ws_size >= wsNeed) {
        // zero counts + ovfcnt in one fill
        hipMemsetAsync(counts, 0, ((size_t)NVOX + 16) * sizeof(int), stream);
        bucket_fill<<<NPRIME / 256, 256, 0, stream>>>(geom, sem, dxp, bxp,
                                                      counts, ovfcnt, ovfbuf,
                                                      bucket);
        bucket_gather<<<NVOX / 64, 256, 0, stream>>>(x, counts, bucket,
                                                     ovfcnt, ovfbuf, out);
    } else {
        hipMemsetAsync(out, 0, (size_t)B_ * C_ * NXY * sizeof(float), stream);
        int nBlocks = (NPRIME * 64 + 255) / 256;
        scatter_direct<<<nBlocks, 256, 0, stream>>>(x, geom, sem, dxp, bxp, out);
    }
}

// Round 2
// 235.993 us; speedup vs baseline: 1.0635x; 1.0042x over previous
//
#include <hip/hip_runtime.h>

// Problem constants (from reference)
#define B_  4
#define N_  1
#define D_  48
#define H_  32
#define W_  88
#define C_  64
#define NX_ 200
#define NY_ 200
#define NZ_ 1
#define NPRIME (B_ * N_ * D_ * H_ * W_)   // 540,672 points
#define NXY    (NX_ * NY_)                // 40,000 bev cells
#define NVOX   (B_ * NXY)                 // 160,000 voxels = 2500 * 64
#define CAP    16                          // bucket capacity (E[n/vox]=1.7)
#define OVFMAX 32768                       // overflow entries (freak-case)

// ---------------------------------------------------------------------------
// Kernel 1 (fused hist+fill): per-point voxel id -> fixed-capacity bucket.
// One thread per point. counts[v] may exceed CAP (gather clamps); extras go
// to the overflow list and are applied exactly by the owning gather block.
// ---------------------------------------------------------------------------
__global__ __launch_bounds__(256)
void bucket_fill(const float* __restrict__ geom,
                 const float* __restrict__ sem,
                 const float* __restrict__ dxp,
                 const float* __restrict__ bxp,
                 int* __restrict__ counts,
                 int* __restrict__ ovfcnt,
                 int* __restrict__ ovfbuf,
                 int* __restrict__ bucket)
{
    int p = blockIdx.x * 256 + threadIdx.x;   // NPRIME = 2112*256 exactly
    int w = p % W_;
    int t = p / W_;
    int h = t % H_;
    int b = (t / H_) / D_;

    float sm = sem[(b * 2 + 1) * (H_ * W_) + h * W_ + w];
    if (!(sm > 0.5f)) return;

    // match reference f32 arithmetic: (geom - (bx - dx/2)) / dx, trunc to 0
    float gxf = (geom[(size_t)p * 3 + 0] - (bxp[0] - dxp[0] * 0.5f)) / dxp[0];
    float gyf = (geom[(size_t)p * 3 + 1] - (bxp[1] - dxp[1] * 0.5f)) / dxp[1];
    float gzf = (geom[(size_t)p * 3 + 2] - (bxp[2] - dxp[2] * 0.5f)) / dxp[2];
    int gx = (int)gxf, gy = (int)gyf, gz = (int)gzf;
    if (gx < 0 || gx >= NX_ || gy < 0 || gy >= NY_ ||
        gz < 0 || gz >= NZ_) return;

    int v = b * NXY + gx * NY_ + gy;          // NZ==1 so gz==0
    int slot = atomicAdd(&counts[v], 1);
    if (slot < CAP) {
        bucket[v * CAP + slot] = p;
    } else {
        int o = atomicAdd(ovfcnt, 1);
        if (o < OVFMAX) { ovfbuf[2 * o] = p; ovfbuf[2 * o + 1] = v; }
    }
}

// ---------------------------------------------------------------------------
// Kernel 2: gather + fused transpose (grouped-float4, round-lean version).
// Block = 256 thr (4 waves) owns 64 voxels; wave owns 16 voxel-chains.
// Wave split into 4 groups of 16 lanes; group g owns chains {4k+g}.
// R2 changes vs R1:
//   - loop bound is the GROUP's max chain length (not the wave's 16-max):
//     E[max4] ~ 4.2 vs E[max16] ~ 6 -> ~30% fewer rounds
//   - bucket slots read as int4 (4 slots/load, 64B-aligned): 4x fewer VMEM
//   - counts read as 4x int4 instead of 16 dwords
//   - dead-round x loads predicated OFF (exec-masked lanes fetch nothing)
// All live indices provably valid (slot < cg[k] <= counts[v] was written by
// fill); safety clamp retained. Then LDS transpose, coalesced store.
// Overflow (normally 0) applied by the owning block AFTER its own stores.
// ---------------------------------------------------------------------------
__global__ __launch_bounds__(256)
void bucket_gather(const float* __restrict__ x,
                   const int* __restrict__ counts,
                   const int* __restrict__ bucket,
                   const int* __restrict__ ovfcnt,
                   const int* __restrict__ ovfbuf,
                   float* __restrict__ out)
{
    __shared__ float tile[64][65];      // [vox][ch], +1 pad
    int blk = blockIdx.x;               // 0..2499
    int t    = threadIdx.x;
    int wave = t >> 6;
    int lane = t & 63;
    int g    = lane >> 4;               // group 0..3
    int s    = lane & 15;               // channel quad: ch 4s..4s+3
    int vbase = blk * 64;
    int b   = vbase / NXY;
    int xy0 = vbase % NXY;
    int v0 = vbase + wave * 16;         // this wave's 16 voxels

    // per-voxel counts, vectorized (v0 is multiple of 16 -> 64B aligned)
    const int4* cp4 = (const int4*)(counts + v0);
    int4 c40 = cp4[0];
    int4 c41 = cp4[1];
    int4 c42 = cp4[2];
    int4 c43 = cp4[3];

    // chain c = 4k+g: count for chain k is component g of c4k
    // (cndmask tree on g, no dynamic indexing -> no scratch)
#define PICKG(v4) ((g & 2) ? ((g & 1) ? (v4).w : (v4).z) \
                           : ((g & 1) ? (v4).y : (v4).x))
    int cg[4];
    cg[0] = min(PICKG(c40), CAP);
    cg[1] = min(PICKG(c41), CAP);
    cg[2] = min(PICKG(c42), CAP);
    cg[3] = min(PICKG(c43), CAP);
#undef PICKG

    int rgmax = max(max(cg[0], cg[1]), max(cg[2], cg[3]));  // group max

    // bucket int4 base per chain: ((v0+4k+g)*CAP)/4 int4s, 64B aligned
    const int4* b4 = (const int4*)bucket;
    int bidx[4];
    #pragma unroll
    for (int k = 0; k < 4; ++k)
        bidx[k] = (v0 + 4 * k + g) * (CAP / 4);

    float4 acc[4];
    #pragma unroll
    for (int k = 0; k < 4; ++k) acc[k] = make_float4(0.f, 0.f, 0.f, 0.f);

    for (int rb = 0; rb < rgmax; rb += 4) {
        int4 e4[4];
        #pragma unroll
        for (int k = 0; k < 4; ++k)
            e4[k] = b4[bidx[k] + (rb >> 2)];
        #pragma unroll
        for (int j = 0; j < 4; ++j) {
            int r = rb + j;
            #pragma unroll
            for (int k = 0; k < 4; ++k) {
                if (r < cg[k]) {         // live slot: index written by fill
                    int e = (j == 0) ? e4[k].x : (j == 1) ? e4[k].y
                          : (j == 2) ? e4[k].z : e4[k].w;
                    e = min(max(e, 0), NPRIME - 1);   // safety clamp
                    float4 v = *(const float4*)(x + (size_t)e * C_ + s * 4);
                    acc[k].x += v.x; acc[k].y += v.y;
                    acc[k].z += v.z; acc[k].w += v.w;
                }
            }
        }
    }

    // tile[row][4s..4s+3] = acc; per-instr bank usage is exactly 2-way (free)
    #pragma unroll
    for (int k = 0; k < 4; ++k) {
        int row = wave * 16 + 4 * k + g;
        tile[row][4 * s + 0] = acc[k].x;
        tile[row][4 * s + 1] = acc[k].y;
        tile[row][4 * s + 2] = acc[k].z;
        tile[row][4 * s + 3] = acc[k].w;
    }
    __syncthreads();

    // transpose out: lane group writes 256 B contiguous runs of (B,C,XY)
    int col = t & 63;                   // xy within tile
    int rg  = t >> 6;                   // 0..3
    float* dst = out + (size_t)b * C_ * NXY + xy0;
    #pragma unroll
    for (int it = 0; it < 16; ++it) {
        int ch = it * 4 + rg;
        dst[(size_t)ch * NXY + col] = tile[col][ch];
    }

    // overflow (freak case; novf == 0 on this data -> one broadcast load)
    int novf = min(ovfcnt[0], OVFMAX);
    if (novf > 0) {
        __syncthreads();                // our stores above now visible
        __threadfence();
        for (int i = 0; i < novf; ++i) {
            int pv = ovfbuf[2 * i + 1];
            int c0 = pv - vbase;
            if (c0 == t) {              // only t<64 can match; owner applies
                int pp = min(max(ovfbuf[2 * i], 0), NPRIME - 1);
                const float* xr = x + (size_t)pp * C_;
                float* d2 = out + (size_t)b * C_ * NXY + xy0 + c0;
                for (int ch = 0; ch < C_; ++ch)
                    atomicAdd(&d2[(size_t)ch * NXY], xr[ch]);
            }
        }
    }
}

// ---------------------------------------------------------------------------
// Fallback (ws tiny): direct strided atomics into out (B, C, NX, NY).
// ---------------------------------------------------------------------------
__global__ __launch_bounds__(256)
void scatter_direct(const float* __restrict__ x,
                    const float* __restrict__ geom,
                    const float* __restrict__ sem,
                    const float* __restrict__ dxp,
                    const float* __restrict__ bxp,
                    float* __restrict__ out)
{
    int gid = blockIdx.x * 256 + threadIdx.x;
    int p = gid >> 6;
    int c = gid & 63;
    if (p >= NPRIME) return;
    int w = p % W_;
    int t = p / W_;
    int h = t % H_;
    t /= H_;
    int b = t / D_;
    float sm = sem[(b * 2 + 1) * (H_ * W_) + h * W_ + w];
    if (!(sm > 0.5f)) return;
    float gxf = (geom[(size_t)p * 3 + 0] - (bxp[0] - dxp[0] * 0.5f)) / dxp[0];
    float gyf = (geom[(size_t)p * 3 + 1] - (bxp[1] - dxp[1] * 0.5f)) / dxp[1];
    float gzf = (geom[(size_t)p * 3 + 2] - (bxp[2] - dxp[2] * 0.5f)) / dxp[2];
    int gx = (int)gxf, gy = (int)gyf, gz = (int)gzf;
    if (gx < 0 || gx >= NX_ || gy < 0 || gy >= NY_ ||
        gz < 0 || gz >= NZ_) return;
    float val = x[(size_t)p * C_ + c];
    atomicAdd(&out[(((size_t)b * C_ + c) * NX_ + gx) * NY_ + gy], val);
}

// ---------------------------------------------------------------------------
extern "C" void kernel_launch(void* const* d_in, const int* in_sizes, int n_in,
                              void* d_out, int out_size, void* d_ws, size_t ws_size,
                              hipStream_t stream)
{
    const float* x    = (const float*)d_in[0];   // (B,N,D,H,W,C)
    const float* geom = (const float*)d_in[1];   // (B,N,D,H,W,3)
    const float* sem  = (const float*)d_in[2];   // (B*N,2,H,W)
    const float* dxp  = (const float*)d_in[3];   // (3,)
    const float* bxp  = (const float*)d_in[4];   // (3,)
    float* out = (float*)d_out;                  // (B, C, NX, NY)

    // ws layout:
    //   [0]            counts   NVOX ints (640 KB) + ovfcnt right after
    //   [1 MiB]        ovfbuf   OVFMAX*2 ints (256 KB)
    //   [2 MiB]        bucket   NVOX*CAP ints (10.24 MiB)
    char* wsb = (char*)d_ws;
    const size_t MB = 1024 * 1024;
    int* counts = (int*)(wsb + 0 * MB);
    int* ovfcnt = counts + NVOX;
    int* ovfbuf = (int*)(wsb + 1 * MB);
    int* bucket = (int*)(wsb + 2 * MB);
    const size_t wsNeed = 2 * MB + (size_t)NVOX * CAP * sizeof(int);

    if (ws_size >= wsNeed) {
        // zero counts + ovfcnt in one fill
        hipMemsetAsync(counts, 0, ((size_t)NVOX + 16) * sizeof(int), stream);
        bucket_fill<<<NPRIME / 256, 256, 0, stream>>>(geom, sem, dxp, bxp,
                                                      counts, ovfcnt, ovfbuf,
                                                      bucket);
        bucket_gather<<<NVOX / 64, 256, 0, stream>>>(x, counts, bucket,
                                                     ovfcnt, ovfbuf, out);
    } else {
        hipMemsetAsync(out, 0, (size_t)B_ * C_ * NXY * sizeof(float), stream);
        int nBlocks = (NPRIME * 64 + 255) / 256;
        scatter_direct<<<nBlocks, 256, 0, stream>>>(x, geom, sem, dxp, bxp, out);
    }
}